// Round 13
// baseline (522.235 us; speedup 1.0000x reference)
//
#include <hip/hip_runtime.h>

#define HW 512
#define PADR 5
#define SEGS 16          // segments per image (ROWS = 32)
#define ROWS 32
#define RING 16          // power-of-2 ring: (i0+k)%16 == k for i0 in {0,16}
#define WPB 2            // waves per block (adjacent segments)
#define NXCD 8

typedef _Float16 h2 __attribute__((ext_vector_type(2)));

__device__ __forceinline__ void load8(const float* __restrict__ p, float v[8]) {
    float4 a = *(const float4*)p;
    float4 b = *(const float4*)(p + 4);
    v[0]=a.x; v[1]=a.y; v[2]=a.z; v[3]=a.w;
    v[4]=b.x; v[5]=b.y; v[6]=b.z; v[7]=b.w;
}

// DPP wave shifts: pure VALU, no DS pipe. bound_ctrl=true zeros invalid lanes;
// callers override lane 0 / lane 63 with selects (replicate padding).
__device__ __forceinline__ float dpp_up1(float x) {   // lane i <- lane i-1
    return __int_as_float(__builtin_amdgcn_update_dpp(
        0, __float_as_int(x), 0x138 /*wave_shr:1*/, 0xf, 0xf, true));
}
__device__ __forceinline__ float dpp_dn1(float x) {   // lane i <- lane i+1
    return __int_as_float(__builtin_amdgcn_update_dpp(
        0, __float_as_int(x), 0x130 /*wave_shl:1*/, 0xf, 0xf, true));
}

__global__ __launch_bounds__(128, 3)
void std_loss_kernel(const float* __restrict__ pred,
                     const float* __restrict__ targ,
                     float* __restrict__ out, float invN, int cpx)
{
    const int lane = threadIdx.x & 63;
    const int wib  = threadIdx.x >> 6;

    // XCD-clustered bijective swizzle (R12): contiguous work chunk per XCD.
    const int bid  = (blockIdx.x % NXCD) * cpx + blockIdx.x / NXCD;

    const int wid  = bid * WPB + wib;
    const int img  = wid / SEGS;
    const int seg  = wid - img * SEGS;

    const float* T = targ + (size_t)img * (HW*HW);
    const float* P = pred + (size_t)img * (HW*HW);

    const int c0 = lane * 8;                 // wave covers the full 512-col row
    const int y0 = seg * ROWS;
    const bool l0  = (lane == 0);
    const bool l63 = (lane == 63);

    // ---- depth-16 fp16 ring of quantized T rows ----
    // invariant: row y0+r lives at slot (r+5)%16; slots 0..10 init to rows
    // y0-5..y0+5; slots 11..15 are written (iter k -> slot (k+11)%16) before
    // first read (center read of slot j happens at iter j-5).
    h2 ring[RING][4];
    float vs[8], vq[8];
    #pragma unroll
    for (int c = 0; c < 8; ++c) { vs[c] = 0.f; vq[c] = 0.f; }
    #pragma unroll
    for (int j = 0; j < 11; ++j) {
        int ry = min(max(y0 - PADR + j, 0), HW - 1);
        float t[8];
        load8(T + ry*HW + c0, t);
        #pragma unroll
        for (int c = 0; c < 4; ++c) {
            h2 v; v.x = (_Float16)t[2*c]; v.y = (_Float16)t[2*c+1];
            ring[j][c] = v;
            float q0 = (float)v.x, q1 = (float)v.y;
            vs[2*c]   += q0; vq[2*c]   = fmaf(q0, q0, vq[2*c]);
            vs[2*c+1] += q1; vq[2*c+1] = fmaf(q1, q1, vq[2*c+1]);
        }
    }

    // ---- explicit 2-deep A/B prefetch pipeline for the two HBM streams ----
    float vnbuf[2][8], pvbuf[2][8];
    load8(T + min(y0 + 0 + PADR + 1, HW-1)*HW + c0, vnbuf[0]);
    load8(P + (y0 + 0)*HW + c0, pvbuf[0]);
    load8(T + min(y0 + 1 + PADR + 1, HW-1)*HW + c0, vnbuf[1]);
    load8(P + (y0 + 1)*HW + c0, pvbuf[1]);

    float acc = 0.f;

    // two passes over the SAME 16-iter unrolled body (I$-friendly); ring
    // indices depend only on k since i0 % RING == 0.
    for (int i0 = 0; i0 < ROWS; i0 += RING) {
        #pragma unroll
        for (int k = 0; k < RING; ++k) {
            const int cur = k & 1;           // == (i0+k)&1, compile-time

            // cross-lane halo via DPP: prev lane's vs[3..7], next lane's vs[0..4]
            float ups[5], upq[5], dns[5], dnq[5];
            #pragma unroll
            for (int t = 0; t < 5; ++t) {
                float a = dpp_up1(vs[3+t]);
                float b = dpp_up1(vq[3+t]);
                float c = dpp_dn1(vs[t]);
                float d = dpp_dn1(vq[t]);
                ups[t] = l0  ? vs[0] : a;
                upq[t] = l0  ? vq[0] : b;
                dns[t] = l63 ? vs[7] : c;
                dnq[t] = l63 ? vq[7] : d;
            }

            float bs = ups[0]+ups[1]+ups[2]+ups[3]+ups[4]
                     + vs[0]+vs[1]+vs[2]+vs[3]+vs[4]+vs[5];
            float bq = upq[0]+upq[1]+upq[2]+upq[3]+upq[4]
                     + vq[0]+vq[1]+vq[2]+vq[3]+vq[4]+vq[5];

            // center row (quantized) for the |p - t| term: slot (k+5)%16
            float tvq[8];
            #pragma unroll
            for (int c = 0; c < 4; ++c) {
                h2 v = ring[(k+5) % RING][c];
                tvq[2*c] = (float)v.x; tvq[2*c+1] = (float)v.y;
            }

            // w = 1 + sqrt(clamp(25*var, 0, 4))
#define EMIT(C) do { \
                float u = bs * (5.0f/121.0f); \
                float t = fmaf(bq, 25.0f/121.0f, -u*u); \
                t = fminf(fmaxf(t, 0.0f), 4.0f); \
                float w = 1.0f + __builtin_amdgcn_sqrtf(t); \
                acc = fmaf(fabsf(pvbuf[cur][C] - tvq[C]), w, acc); \
            } while (0)

            EMIT(0);
            bs += vs[6]  - ups[0];  bq += vq[6]  - upq[0];  EMIT(1);
            bs += vs[7]  - ups[1];  bq += vq[7]  - upq[1];  EMIT(2);
            bs += dns[0] - ups[2];  bq += dnq[0] - upq[2];  EMIT(3);
            bs += dns[1] - ups[3];  bq += dnq[1] - upq[3];  EMIT(4);
            bs += dns[2] - ups[4];  bq += dnq[2] - upq[4];  EMIT(5);
            bs += dns[3] - vs[0];   bq += dnq[3] - vq[0];   EMIT(6);
            bs += dns[4] - vs[1];   bq += dnq[4] - vq[1];   EMIT(7);
#undef EMIT

            // slide: remove slot k (row y-5), insert quantized vn at slot (k+11)%16
            #pragma unroll
            for (int c = 0; c < 4; ++c) {
                h2 nv; nv.x = (_Float16)vnbuf[cur][2*c]; nv.y = (_Float16)vnbuf[cur][2*c+1];
                h2 ov = ring[k][c];
                float n0 = (float)nv.x, n1 = (float)nv.y;
                float o0 = (float)ov.x, o1 = (float)ov.y;
                float d0 = n0 - o0, d1 = n1 - o1;
                vs[2*c]   += d0;  vq[2*c]   = fmaf(d0, n0 + o0, vq[2*c]);
                vs[2*c+1] += d1;  vq[2*c+1] = fmaf(d1, n1 + o1, vq[2*c+1]);
                ring[(k+11) % RING][c] = nv;
            }

            // buffer `cur` now free: issue iter i+2's loads (wave-uniform guard)
            if (i0 + k + 2 < ROWS) {
                const int yn = y0 + i0 + k + 2;
                load8(T + min(yn + PADR + 1, HW-1)*HW + c0, vnbuf[cur]);
                load8(P + yn*HW + c0, pvbuf[cur]);
            }
        }
    }

    // wave reduce
    #pragma unroll
    for (int off = 32; off > 0; off >>= 1)
        acc += __shfl_down(acc, off, 64);

    __shared__ float wsum[WPB];
    if (lane == 0) wsum[wib] = acc;
    __syncthreads();
    if (threadIdx.x == 0) {
        float s = 0.f;
        #pragma unroll
        for (int i = 0; i < WPB; ++i) s += wsum[i];
        atomicAdd(out, s * invN);
    }
}

extern "C" void kernel_launch(void* const* d_in, const int* in_sizes, int n_in,
                              void* d_out, int out_size, void* d_ws, size_t ws_size,
                              hipStream_t stream) {
    const float* pred = (const float*)d_in[0];
    const float* targ = (const float*)d_in[1];
    float* out = (float*)d_out;

    const int nimg = in_sizes[1] / (HW * HW);       // 96 for (32,3,512,512)
    const float invN = 1.0f / (float)in_sizes[1];

    (void)hipMemsetAsync(out, 0, sizeof(float), stream);  // capture-legal memset node

    const int nblocks = nimg * SEGS / WPB;          // 768 (divisible by 8)
    const int cpx = nblocks / NXCD;                 // 96 blocks per XCD chunk
    std_loss_kernel<<<nblocks, 128, 0, stream>>>(pred, targ, out, invN, cpx);
}

// Round 14
// 46.029 us; speedup vs baseline: 11.3459x; 11.3459x over previous
//
#include <hip/hip_runtime.h>

#define HW 512
#define PADR 5
#define SEGS 16          // segments per image (ROWS = 32)
#define ROWS 32
#define WPB 2            // waves per block (adjacent segments)
#define NXCD 8

typedef _Float16 h2 __attribute__((ext_vector_type(2)));

__device__ __forceinline__ void load8(const float* __restrict__ p, float v[8]) {
    float4 a = *(const float4*)p;
    float4 b = *(const float4*)(p + 4);
    v[0]=a.x; v[1]=a.y; v[2]=a.z; v[3]=a.w;
    v[4]=b.x; v[5]=b.y; v[6]=b.z; v[7]=b.w;
}

// DPP wave shifts: pure VALU, no DS pipe. bound_ctrl=true zeros invalid lanes;
// callers override lane 0 / lane 63 with selects (replicate padding).
__device__ __forceinline__ float dpp_up1(float x) {   // lane i <- lane i-1
    return __int_as_float(__builtin_amdgcn_update_dpp(
        0, __float_as_int(x), 0x138 /*wave_shr:1*/, 0xf, 0xf, true));
}
__device__ __forceinline__ float dpp_dn1(float x) {   // lane i <- lane i+1
    return __int_as_float(__builtin_amdgcn_update_dpp(
        0, __float_as_int(x), 0x130 /*wave_shl:1*/, 0xf, 0xf, true));
}

__global__ __launch_bounds__(128)
void std_loss_kernel(const float* __restrict__ pred,
                     const float* __restrict__ targ,
                     float* __restrict__ out, float invN, int cpx)
{
    const int lane = threadIdx.x & 63;
    const int wib  = threadIdx.x >> 6;

    // XCD-clustered bijective swizzle (R12): contiguous work chunk per XCD.
    const int bid  = (blockIdx.x % NXCD) * cpx + blockIdx.x / NXCD;

    const int wid  = bid * WPB + wib;
    const int img  = wid / SEGS;
    const int seg  = wid - img * SEGS;

    const float* T = targ + (size_t)img * (HW*HW);
    const float* P = pred + (size_t)img * (HW*HW);

    const int c0 = lane * 8;                 // wave covers the full 512-col row
    const int y0 = seg * ROWS;
    const bool l0  = (lane == 0);
    const bool l63 = (lane == 63);

    // ---- 11-row fp16-packed register FIFO (fully-unrolled loop -> SROA to regs)
    h2 fifo[11][4];
    float vs[8], vq[8];
    #pragma unroll
    for (int c = 0; c < 8; ++c) { vs[c] = 0.f; vq[c] = 0.f; }
    #pragma unroll
    for (int j = 0; j < 11; ++j) {
        int ry = min(max(y0 - PADR + j, 0), HW - 1);
        float t[8];
        load8(T + ry*HW + c0, t);
        #pragma unroll
        for (int c = 0; c < 4; ++c) {
            h2 v; v.x = (_Float16)t[2*c]; v.y = (_Float16)t[2*c+1];
            fifo[j][c] = v;
            float q0 = (float)v.x, q1 = (float)v.y;
            vs[2*c]   += q0; vq[2*c]   = fmaf(q0, q0, vq[2*c]);
            vs[2*c+1] += q1; vq[2*c+1] = fmaf(q1, q1, vq[2*c+1]);
        }
    }

    // ---- explicit 2-deep A/B prefetch pipeline for the two HBM streams ----
    float vnbuf[2][8], pvbuf[2][8];
    load8(T + min(y0 + 0 + PADR + 1, HW-1)*HW + c0, vnbuf[0]);
    load8(P + (y0 + 0)*HW + c0, pvbuf[0]);
    load8(T + min(y0 + 1 + PADR + 1, HW-1)*HW + c0, vnbuf[1]);
    load8(P + (y0 + 1)*HW + c0, pvbuf[1]);

    float acc = 0.f;

    #pragma unroll
    for (int i = 0; i < ROWS; ++i) {         // FULL unroll: all indices static
        const int cur = i & 1;

        // cross-lane halo via DPP: prev lane's vs[3..7], next lane's vs[0..4]
        float ups[5], upq[5], dns[5], dnq[5];
        #pragma unroll
        for (int k = 0; k < 5; ++k) {
            float a = dpp_up1(vs[3+k]);
            float b = dpp_up1(vq[3+k]);
            float c = dpp_dn1(vs[k]);
            float d = dpp_dn1(vq[k]);
            ups[k] = l0  ? vs[0] : a;
            upq[k] = l0  ? vq[0] : b;
            dns[k] = l63 ? vs[7] : c;
            dnq[k] = l63 ? vq[7] : d;
        }

        float bs = ups[0]+ups[1]+ups[2]+ups[3]+ups[4]
                 + vs[0]+vs[1]+vs[2]+vs[3]+vs[4]+vs[5];
        float bq = upq[0]+upq[1]+upq[2]+upq[3]+upq[4]
                 + vq[0]+vq[1]+vq[2]+vq[3]+vq[4]+vq[5];

        // center row (quantized) for the |p - t| term
        float tvq[8];
        #pragma unroll
        for (int c = 0; c < 4; ++c) {
            h2 v = fifo[(i+5) % 11][c];
            tvq[2*c] = (float)v.x; tvq[2*c+1] = (float)v.y;
        }

        // w = 1 + sqrt(clamp(25*var, 0, 4));  25*var = bq*25/121 - (bs*5/121)^2
#define EMIT(C) do { \
            float u = bs * (5.0f/121.0f); \
            float t = fmaf(bq, 25.0f/121.0f, -u*u); \
            t = fminf(fmaxf(t, 0.0f), 4.0f); \
            float w = 1.0f + __builtin_amdgcn_sqrtf(t); \
            acc = fmaf(fabsf(pvbuf[cur][C] - tvq[C]), w, acc); \
        } while (0)

        EMIT(0);
        bs += vs[6]  - ups[0];  bq += vq[6]  - upq[0];  EMIT(1);
        bs += vs[7]  - ups[1];  bq += vq[7]  - upq[1];  EMIT(2);
        bs += dns[0] - ups[2];  bq += dnq[0] - upq[2];  EMIT(3);
        bs += dns[1] - ups[3];  bq += dnq[1] - upq[3];  EMIT(4);
        bs += dns[2] - ups[4];  bq += dnq[2] - upq[4];  EMIT(5);
        bs += dns[3] - vs[0];   bq += dnq[3] - vq[0];   EMIT(6);
        bs += dns[4] - vs[1];   bq += dnq[4] - vq[1];   EMIT(7);
#undef EMIT

        // slide window: quantize incoming row, +quantized(y+6), -fifo slot (y-5)
        #pragma unroll
        for (int c = 0; c < 4; ++c) {
            h2 nv; nv.x = (_Float16)vnbuf[cur][2*c]; nv.y = (_Float16)vnbuf[cur][2*c+1];
            h2 ov = fifo[i % 11][c];
            float n0 = (float)nv.x, n1 = (float)nv.y;
            float o0 = (float)ov.x, o1 = (float)ov.y;
            float d0 = n0 - o0, d1 = n1 - o1;
            vs[2*c]   += d0;  vq[2*c]   = fmaf(d0, n0 + o0, vq[2*c]);
            vs[2*c+1] += d1;  vq[2*c+1] = fmaf(d1, n1 + o1, vq[2*c+1]);
            fifo[i % 11][c] = nv;
        }

        // buffer `cur` is free: issue iter i+2's loads (static guard)
        if (i + 2 < ROWS) {
            load8(T + min(y0 + (i+2) + PADR + 1, HW-1)*HW + c0, vnbuf[cur]);
            load8(P + (y0 + (i+2))*HW + c0, pvbuf[cur]);
        }
    }

    // wave reduce
    #pragma unroll
    for (int off = 32; off > 0; off >>= 1)
        acc += __shfl_down(acc, off, 64);

    __shared__ float wsum[WPB];
    if (lane == 0) wsum[wib] = acc;
    __syncthreads();
    if (threadIdx.x == 0) {
        float s = 0.f;
        #pragma unroll
        for (int i = 0; i < WPB; ++i) s += wsum[i];
        atomicAdd(out, s * invN);
    }
}

extern "C" void kernel_launch(void* const* d_in, const int* in_sizes, int n_in,
                              void* d_out, int out_size, void* d_ws, size_t ws_size,
                              hipStream_t stream) {
    const float* pred = (const float*)d_in[0];
    const float* targ = (const float*)d_in[1];
    float* out = (float*)d_out;

    const int nimg = in_sizes[1] / (HW * HW);       // 96 for (32,3,512,512)
    const float invN = 1.0f / (float)in_sizes[1];

    (void)hipMemsetAsync(out, 0, sizeof(float), stream);  // capture-legal memset node

    const int nblocks = nimg * SEGS / WPB;          // 768 (divisible by 8)
    const int cpx = nblocks / NXCD;                 // 96 blocks per XCD chunk
    std_loss_kernel<<<nblocks, 128, 0, stream>>>(pred, targ, out, invN, cpx);
}